// Round 1
// baseline (35770.163 us; speedup 1.0000x reference)
//
#include <hip/hip_runtime.h>
#include <hip/hip_bf16.h>
#include <stdint.h>

#define BATCH  64
#define SEQ    1024
#define EMBED  128
#define HIDDEN 512
#define VOCAB  256

using bf16 = __hip_bfloat16;
typedef __attribute__((ext_vector_type(8))) short bf16x8;
typedef __attribute__((ext_vector_type(4))) float f32x4;

__device__ __forceinline__ float bflo(unsigned u) { return __uint_as_float(u << 16); }
__device__ __forceinline__ float bfhi(unsigned u) { return __uint_as_float(u & 0xffff0000u); }

// ---------------- weight converts ----------------
__global__ void k_cvt(const float* __restrict__ in, bf16* __restrict__ out, int n) {
    int i = blockIdx.x * 256 + threadIdx.x;
    if (i < n) out[i] = __float2bfloat16(in[i]);
}

// W_xh [EMBED][HIDDEN] (k-major) -> wxh_t [HIDDEN][EMBED] (n-major, "B^T" layout)
__global__ void k_txp_wxh(const float* __restrict__ in, bf16* __restrict__ out) {
    int idx = blockIdx.x * 256 + threadIdx.x;   // 65536
    int e = idx >> 9, j = idx & 511;            // in[e*512 + j], coalesced read
    out[j * EMBED + e] = __float2bfloat16(in[idx]);
}

// ---------------- bf16 MFMA GEMM:  C[M][N] = A[M][K] * B'[N][K]^T + bias ----------------
// BM=BN=BK=64, 4 waves, 16x16x32 MFMA. B is pre-transposed ([N][K]) so both A and B
// fragments are 8 contiguous-K bf16 (one ds_read_b128 each).
template<bool GATHER, bool OUT_BF16>
__global__ __launch_bounds__(256) void k_gemm(
    const bf16* __restrict__ A,       // [M][K]; if GATHER: embedding table [VOCAB][K]
    const int*  __restrict__ xtok,    // tokens [BATCH][SEQ] (GATHER only)
    const bf16* __restrict__ B,       // [N][K]
    const float* __restrict__ bias,   // [N]
    float* __restrict__ Cf,
    bf16*  __restrict__ Cb,
    int M, int N, int K)
{
    __shared__ bf16 As[64][72];   // +8 bf16 pad: row stride 144B (16B-aligned, ~2-way banks)
    __shared__ bf16 Bs[64][72];
    const int m0 = blockIdx.x * 64, n0 = blockIdx.y * 64;
    const int tid  = threadIdx.x;
    const int lane = tid & 63, wid = tid >> 6;
    const int wm = wid >> 1, wn = wid & 1;        // 2x2 wave grid, 32x32 each
    const int lrow = tid >> 3, lc8 = tid & 7;     // staging: 8 threads x 16B per row

    f32x4 acc[2][2] = {};

    for (int k0 = 0; k0 < K; k0 += 64) {
#pragma unroll
        for (int pass = 0; pass < 2; ++pass) {
            int row = pass * 32 + lrow;
            const bf16* asrc;
            if (GATHER) {
                int m = m0 + row;                 // m = t*BATCH + b
                int t = m >> 6, bb = m & 63;
                int tok = xtok[bb * SEQ + t];
                asrc = A + (size_t)tok * K + k0 + lc8 * 8;
            } else {
                asrc = A + (size_t)(m0 + row) * K + k0 + lc8 * 8;
            }
            *reinterpret_cast<uint4*>(&As[row][lc8 * 8]) = *reinterpret_cast<const uint4*>(asrc);
            *reinterpret_cast<uint4*>(&Bs[row][lc8 * 8]) =
                *reinterpret_cast<const uint4*>(B + (size_t)(n0 + row) * K + k0 + lc8 * 8);
        }
        __syncthreads();
#pragma unroll
        for (int kk = 0; kk < 2; ++kk) {
            bf16x8 af[2], bg[2];
#pragma unroll
            for (int mt = 0; mt < 2; ++mt)
                af[mt] = *reinterpret_cast<const bf16x8*>(
                    &As[wm * 32 + mt * 16 + (lane & 15)][kk * 32 + (lane >> 4) * 8]);
#pragma unroll
            for (int nt = 0; nt < 2; ++nt)
                bg[nt] = *reinterpret_cast<const bf16x8*>(
                    &Bs[wn * 32 + nt * 16 + (lane & 15)][kk * 32 + (lane >> 4) * 8]);
#pragma unroll
            for (int mt = 0; mt < 2; ++mt)
#pragma unroll
                for (int nt = 0; nt < 2; ++nt)
                    acc[mt][nt] = __builtin_amdgcn_mfma_f32_16x16x32_bf16(
                        af[mt], bg[nt], acc[mt][nt], 0, 0, 0);
        }
        __syncthreads();
    }
    // epilogue: D lane map col=lane&15, row=(lane>>4)*4+reg  [m89-verified]
#pragma unroll
    for (int mt = 0; mt < 2; ++mt) {
        int rbase = m0 + wm * 32 + mt * 16 + (lane >> 4) * 4;
#pragma unroll
        for (int nt = 0; nt < 2; ++nt) {
            int col = n0 + wn * 32 + nt * 16 + (lane & 15);
            float bv = bias[col];
#pragma unroll
            for (int r = 0; r < 4; ++r) {
                float v = acc[mt][nt][r] + bv;
                size_t off = (size_t)(rbase + r) * N + col;
                if (OUT_BF16) Cb[off] = __float2bfloat16(v);
                else          Cf[off] = v;
            }
        }
    }
}

// ---------------- sequential scan: one block per batch row ----------------
// 512 threads: thread = (is = tid>>6 : K-slice of 64, js = tid&63 : 8-column octet).
// W_hh (bf16, 512KB) streamed from L2 each step; h lives in LDS (f32 master copy).
__global__ __launch_bounds__(512) void k_scan(
    const bf16* __restrict__ xwb,   // [SEQ][BATCH][HIDDEN]
    const bf16* __restrict__ whh,   // [HIDDEN][HIDDEN]
    const float* __restrict__ h0,   // [BATCH][HIDDEN]
    bf16* __restrict__ hh,          // [BATCH][SEQ][HIDDEN]
    float* __restrict__ hfin)       // [BATCH][HIDDEN]
{
    __shared__ float h[HIDDEN];
    __shared__ float part[8][HIDDEN];
    const int b   = blockIdx.x;
    const int tid = threadIdx.x;
    const int is  = tid >> 6;
    const int js  = tid & 63;

    h[tid] = h0[b * HIDDEN + tid];
    __syncthreads();

    // uint4 = 8 bf16 = W row segment [8*js .. 8*js+7]; row stride = HIDDEN/8 uint4
    const uint4* wbase = reinterpret_cast<const uint4*>(whh) + (size_t)(is * 64) * (HIDDEN / 8) + js;

    for (int t = 0; t < SEQ; ++t) {
        // preload this thread's 64 h values (LDS broadcast reads, b128)
        float hr[64];
#pragma unroll
        for (int q = 0; q < 16; ++q)
            *reinterpret_cast<float4*>(&hr[q * 4]) =
                *reinterpret_cast<const float4*>(&h[is * 64 + q * 4]);

        float acc[8] = {0.f, 0.f, 0.f, 0.f, 0.f, 0.f, 0.f, 0.f};
#pragma unroll
        for (int i = 0; i < 64; ++i) {
            uint4 w = wbase[(size_t)i * (HIDDEN / 8)];
            float hv = hr[i];
            acc[0] = fmaf(hv, bflo(w.x), acc[0]);
            acc[1] = fmaf(hv, bfhi(w.x), acc[1]);
            acc[2] = fmaf(hv, bflo(w.y), acc[2]);
            acc[3] = fmaf(hv, bfhi(w.y), acc[3]);
            acc[4] = fmaf(hv, bflo(w.z), acc[4]);
            acc[5] = fmaf(hv, bfhi(w.z), acc[5]);
            acc[6] = fmaf(hv, bflo(w.w), acc[6]);
            acc[7] = fmaf(hv, bfhi(w.w), acc[7]);
        }
#pragma unroll
        for (int q = 0; q < 8; ++q) part[is][js * 8 + q] = acc[q];
        __syncthreads();

        // reduce K-slices, add xw, tanh, update h
        float s = part[0][tid];
#pragma unroll
        for (int r = 1; r < 8; ++r) s += part[r][tid];
        float pre = s + __bfloat162float(xwb[((size_t)t * BATCH + b) * HIDDEN + tid]);
        float e2  = __expf(2.f * pre);
        float hn  = 1.f - 2.f / (e2 + 1.f);        // tanh(pre)
        h[tid] = hn;   // safe: all reads of h happened before the barrier above
        hh[((size_t)b * SEQ + t) * HIDDEN + tid] = __float2bfloat16(hn);
        __syncthreads();
    }
    hfin[b * HIDDEN + tid] = h[tid];
}

// ---------------- launch ----------------
extern "C" void kernel_launch(void* const* d_in, const int* in_sizes, int n_in,
                              void* d_out, int out_size, void* d_ws, size_t ws_size,
                              hipStream_t stream) {
    const int*   x    = (const int*)  d_in[0];
    const float* h0   = (const float*)d_in[1];
    const float* emb  = (const float*)d_in[2];
    const float* wxh  = (const float*)d_in[3];
    const float* whh  = (const float*)d_in[4];
    const float* bh   = (const float*)d_in[5];
    const float* whyw = (const float*)d_in[6];
    const float* whyb = (const float*)d_in[7];

    float* logits = (float*)d_out;                            // [BATCH][SEQ][VOCAB]
    float* hfin   = logits + (size_t)BATCH * SEQ * VOCAB;     // [BATCH][HIDDEN]

    // workspace carve (~135 MB)
    char* p = (char*)d_ws;
    bf16* xwb    = (bf16*)p; p += (size_t)SEQ * BATCH * HIDDEN * 2;
    bf16* hh     = (bf16*)p; p += (size_t)BATCH * SEQ * HIDDEN * 2;
    bf16* whh_bf = (bf16*)p; p += (size_t)HIDDEN * HIDDEN * 2;
    bf16* wxh_t  = (bf16*)p; p += (size_t)HIDDEN * EMBED * 2;
    bf16* emb_bf = (bf16*)p; p += (size_t)VOCAB * EMBED * 2;
    bf16* why_bf = (bf16*)p; p += (size_t)VOCAB * HIDDEN * 2;

    k_cvt<<<(HIDDEN * HIDDEN + 255) / 256, 256, 0, stream>>>(whh, whh_bf, HIDDEN * HIDDEN);
    k_cvt<<<(VOCAB * EMBED + 255) / 256, 256, 0, stream>>>(emb, emb_bf, VOCAB * EMBED);
    k_cvt<<<(VOCAB * HIDDEN + 255) / 256, 256, 0, stream>>>(whyw, why_bf, VOCAB * HIDDEN);
    k_txp_wxh<<<(EMBED * HIDDEN + 255) / 256, 256, 0, stream>>>(wxh, wxh_t);

    // phase 1: xwb[t*64+b][j] = emb[x[b][t]] @ W_xh + b_h
    k_gemm<true, true><<<dim3((SEQ * BATCH) / 64, HIDDEN / 64), 256, 0, stream>>>(
        emb_bf, x, wxh_t, bh, nullptr, xwb, SEQ * BATCH, HIDDEN, EMBED);

    // phase 2: the recurrence
    k_scan<<<BATCH, HIDDEN, 0, stream>>>(xwb, whh_bf, h0, hh, hfin);

    // phase 3: logits[b*1024+t][v] = hh @ W_hy^T + b
    k_gemm<false, false><<<dim3((BATCH * SEQ) / 64, VOCAB / 64), 256, 0, stream>>>(
        hh, nullptr, why_bf, whyb, logits, nullptr, BATCH * SEQ, VOCAB, HIDDEN);
}

// Round 3
// 3937.162 us; speedup vs baseline: 9.0853x; 9.0853x over previous
//
#include <hip/hip_runtime.h>
#include <hip/hip_bf16.h>
#include <stdint.h>

#define BATCH  64
#define SEQ    1024
#define EMBED  128
#define HIDDEN 512
#define VOCAB  256

using bf16 = __hip_bfloat16;
typedef __attribute__((ext_vector_type(8))) short bf16x8;
typedef __attribute__((ext_vector_type(4))) float f32x4;

// ---------------- weight converts ----------------
__global__ void k_cvt(const float* __restrict__ in, bf16* __restrict__ out, int n) {
    int i = blockIdx.x * 256 + threadIdx.x;
    if (i < n) out[i] = __float2bfloat16(in[i]);
}

// W_xh [EMBED][HIDDEN] -> wxh_t [HIDDEN][EMBED] bf16
__global__ void k_txp_wxh(const float* __restrict__ in, bf16* __restrict__ out) {
    int idx = blockIdx.x * 256 + threadIdx.x;   // 65536
    int e = idx >> 9, j = idx & 511;
    out[j * EMBED + e] = __float2bfloat16(in[idx]);
}

// W_hh [K=512][N=512] -> wt [N=512][K=512] bf16
__global__ void k_txp_whh(const float* __restrict__ in, bf16* __restrict__ out) {
    int idx = blockIdx.x * 256 + threadIdx.x;   // 262144
    int k = idx >> 9, n = idx & 511;
    out[n * HIDDEN + k] = __float2bfloat16(in[idx]);
}

// ---------------- bf16 MFMA GEMM:  C[M][N] = A[M][K] * B'[N][K]^T + bias ----------------
template<bool GATHER, bool OUT_BF16>
__global__ __launch_bounds__(256) void k_gemm(
    const bf16* __restrict__ A,       // [M][K]; if GATHER: embedding table [VOCAB][K]
    const int*  __restrict__ xtok,    // tokens [BATCH][SEQ] (GATHER only)
    const bf16* __restrict__ B,       // [N][K]
    const float* __restrict__ bias,   // [N]
    float* __restrict__ Cf,
    bf16*  __restrict__ Cb,
    int M, int N, int K)
{
    __shared__ bf16 As[64][72];
    __shared__ bf16 Bs[64][72];
    const int m0 = blockIdx.x * 64, n0 = blockIdx.y * 64;
    const int tid  = threadIdx.x;
    const int lane = tid & 63, wid = tid >> 6;
    const int wm = wid >> 1, wn = wid & 1;
    const int lrow = tid >> 3, lc8 = tid & 7;

    f32x4 acc[2][2] = {};

    for (int k0 = 0; k0 < K; k0 += 64) {
#pragma unroll
        for (int pass = 0; pass < 2; ++pass) {
            int row = pass * 32 + lrow;
            const bf16* asrc;
            if (GATHER) {
                int m = m0 + row;                 // m = t*BATCH + b
                int t = m >> 6, bb = m & 63;
                int tok = xtok[bb * SEQ + t];
                asrc = A + (size_t)tok * K + k0 + lc8 * 8;
            } else {
                asrc = A + (size_t)(m0 + row) * K + k0 + lc8 * 8;
            }
            *reinterpret_cast<uint4*>(&As[row][lc8 * 8]) = *reinterpret_cast<const uint4*>(asrc);
            *reinterpret_cast<uint4*>(&Bs[row][lc8 * 8]) =
                *reinterpret_cast<const uint4*>(B + (size_t)(n0 + row) * K + k0 + lc8 * 8);
        }
        __syncthreads();
#pragma unroll
        for (int kk = 0; kk < 2; ++kk) {
            bf16x8 af[2], bg[2];
#pragma unroll
            for (int mt = 0; mt < 2; ++mt)
                af[mt] = *reinterpret_cast<const bf16x8*>(
                    &As[wm * 32 + mt * 16 + (lane & 15)][kk * 32 + (lane >> 4) * 8]);
#pragma unroll
            for (int nt = 0; nt < 2; ++nt)
                bg[nt] = *reinterpret_cast<const bf16x8*>(
                    &Bs[wn * 32 + nt * 16 + (lane & 15)][kk * 32 + (lane >> 4) * 8]);
#pragma unroll
            for (int mt = 0; mt < 2; ++mt)
#pragma unroll
                for (int nt = 0; nt < 2; ++nt)
                    acc[mt][nt] = __builtin_amdgcn_mfma_f32_16x16x32_bf16(
                        af[mt], bg[nt], acc[mt][nt], 0, 0, 0);
        }
        __syncthreads();
    }
#pragma unroll
    for (int mt = 0; mt < 2; ++mt) {
        int rbase = m0 + wm * 32 + mt * 16 + (lane >> 4) * 4;
#pragma unroll
        for (int nt = 0; nt < 2; ++nt) {
            int col = n0 + wn * 32 + nt * 16 + (lane & 15);
            float bv = bias[col];
#pragma unroll
            for (int r = 0; r < 4; ++r) {
                float v = acc[mt][nt][r] + bv;
                size_t off = (size_t)(rbase + r) * N + col;
                if (OUT_BF16) Cb[off] = __float2bfloat16(v);
                else          Cf[off] = v;
            }
        }
    }
}

// ---------------- MFMA scan: 4 blocks x 16 batch rows, no cross-block sync ----------------
// 8 waves/block; wave w owns N-columns [64w, 64w+64). Per step: one 16x512x512 GEMM.
// wt [N][K] bf16: K-rows [0,96) LDS-resident, [96,512) streamed from (XCD-private) L2
// as direct per-fragment global_load_dwordx4 (52 independent loads/wave/step).
#define ROWS 16
#define KRES 96                 // resident K (3 k-chunks of 32)
#define WRES_STRIDE (KRES + 8)  // +8 bf16 pad -> 2-way banks (free)
#define H_STRIDE (HIDDEN + 8)

__global__ __launch_bounds__(512) void k_scan_mfma(
    const bf16* __restrict__ xwb,   // [SEQ][BATCH][HIDDEN]
    const bf16* __restrict__ wt,    // [HIDDEN n][HIDDEN k]
    const float* __restrict__ h0,   // [BATCH][HIDDEN]
    bf16* __restrict__ hh,          // [BATCH][SEQ][HIDDEN]
    float* __restrict__ hfin)       // [BATCH][HIDDEN]
{
    __shared__ bf16 wres[HIDDEN * WRES_STRIDE];   // 104 KB
    __shared__ bf16 h_lds[ROWS * H_STRIDE];       // 16.25 KB
    __shared__ bf16 xw_lds[ROWS * H_STRIDE];      // 16.25 KB

    const int tid  = threadIdx.x;
    const int lane = tid & 63, wid = tid >> 6;
    const int b0   = blockIdx.x * ROWS;
    const int n0w  = wid * 64;
    const int lm   = lane & 15, lk = lane >> 4;

    // ---- one-time init: resident W rows (each thread owns one n-row) ----
    {
        const bf16* src = wt + (size_t)tid * HIDDEN;
        bf16* dst = &wres[tid * WRES_STRIDE];
#pragma unroll
        for (int j = 0; j < KRES / 8; ++j)
            *reinterpret_cast<uint4*>(dst + j * 8) =
                *reinterpret_cast<const uint4*>(src + j * 8);
    }
    // ---- one-time init: h state ----
    {
        int row = tid >> 5, c = (tid & 31) * 16;
        const float* src = h0 + (size_t)(b0 + row) * HIDDEN + c;
        bf16 tmp[16];
#pragma unroll
        for (int j = 0; j < 16; ++j) tmp[j] = __float2bfloat16(src[j]);
        *reinterpret_cast<uint4*>(&h_lds[row * H_STRIDE + c])     = *reinterpret_cast<uint4*>(&tmp[0]);
        *reinterpret_cast<uint4*>(&h_lds[row * H_STRIDE + c + 8]) = *reinterpret_cast<uint4*>(&tmp[8]);
    }
    __syncthreads();

    const int xrow = tid >> 5, xc = (tid & 31) * 8;   // xw staging slots

    for (int t = 0; t < SEQ; ++t) {
        // stage xw(t) global->reg early; latency hides under the MFMA phase
        const bf16* xsrc = xwb + ((size_t)t * BATCH + b0 + xrow) * HIDDEN;
        uint4 xv0 = *reinterpret_cast<const uint4*>(xsrc + xc);
        uint4 xv1 = *reinterpret_cast<const uint4*>(xsrc + xc + 256);

        // A fragments: full-K h for this step (2-way banks via pad)
        bf16x8 af[16];
#pragma unroll
        for (int kc = 0; kc < 16; ++kc)
            af[kc] = *reinterpret_cast<const bf16x8*>(
                &h_lds[lm * H_STRIDE + kc * 32 + lk * 8]);

        f32x4 acc[4];
#pragma unroll
        for (int nt = 0; nt < 4; ++nt) {
            acc[nt] = (f32x4){0.f, 0.f, 0.f, 0.f};
            const int row = n0w + nt * 16 + lm;
            const bf16* lsrc = &wres[row * WRES_STRIDE + lk * 8];
            const bf16* gsrc = wt + (size_t)row * HIDDEN + lk * 8;
#pragma unroll
            for (int kc = 0; kc < 3; ++kc) {
                bf16x8 bg = *reinterpret_cast<const bf16x8*>(lsrc + kc * 32);
                acc[nt] = __builtin_amdgcn_mfma_f32_16x16x32_bf16(af[kc], bg, acc[nt], 0, 0, 0);
            }
#pragma unroll
            for (int kc = 3; kc < 16; ++kc) {
                bf16x8 bg = *reinterpret_cast<const bf16x8*>(gsrc + kc * 32);
                acc[nt] = __builtin_amdgcn_mfma_f32_16x16x32_bf16(af[kc], bg, acc[nt], 0, 0, 0);
            }
        }
        // park staged xw in LDS for the epilogue
        *reinterpret_cast<uint4*>(&xw_lds[xrow * H_STRIDE + xc])       = xv0;
        *reinterpret_cast<uint4*>(&xw_lds[xrow * H_STRIDE + xc + 256]) = xv1;
        __syncthreads();

        // epilogue: pre-act -> tanh -> update h (D map: col=lane&15, row=(lane>>4)*4+r)
#pragma unroll
        for (int nt = 0; nt < 4; ++nt) {
            int col = n0w + nt * 16 + lm;
#pragma unroll
            for (int r = 0; r < 4; ++r) {
                int m = lk * 4 + r;
                float pre = acc[nt][r] + __bfloat162float(xw_lds[m * H_STRIDE + col]);
                float e2  = __expf(2.f * pre);
                float hn  = 1.f - 2.f / (e2 + 1.f);     // tanh(pre)
                bf16 hb   = __float2bfloat16(hn);
                h_lds[m * H_STRIDE + col] = hb;
                hh[((size_t)(b0 + m) * SEQ + t) * HIDDEN + col] = hb;
                if (t == SEQ - 1) hfin[(size_t)(b0 + m) * HIDDEN + col] = hn;
            }
        }
        __syncthreads();
    }
}

// ---------------- launch ----------------
extern "C" void kernel_launch(void* const* d_in, const int* in_sizes, int n_in,
                              void* d_out, int out_size, void* d_ws, size_t ws_size,
                              hipStream_t stream) {
    const int*   x    = (const int*)  d_in[0];
    const float* h0   = (const float*)d_in[1];
    const float* emb  = (const float*)d_in[2];
    const float* wxh  = (const float*)d_in[3];
    const float* whh  = (const float*)d_in[4];
    const float* bh   = (const float*)d_in[5];
    const float* whyw = (const float*)d_in[6];
    const float* whyb = (const float*)d_in[7];

    float* logits = (float*)d_out;                            // [BATCH][SEQ][VOCAB]
    float* hfin   = logits + (size_t)BATCH * SEQ * VOCAB;     // [BATCH][HIDDEN]

    char* p = (char*)d_ws;
    bf16* xwb    = (bf16*)p; p += (size_t)SEQ * BATCH * HIDDEN * 2;
    bf16* hh     = (bf16*)p; p += (size_t)BATCH * SEQ * HIDDEN * 2;
    bf16* wt     = (bf16*)p; p += (size_t)HIDDEN * HIDDEN * 2;
    bf16* wxh_t  = (bf16*)p; p += (size_t)HIDDEN * EMBED * 2;
    bf16* emb_bf = (bf16*)p; p += (size_t)VOCAB * EMBED * 2;
    bf16* why_bf = (bf16*)p; p += (size_t)VOCAB * HIDDEN * 2;

    k_txp_whh<<<(HIDDEN * HIDDEN + 255) / 256, 256, 0, stream>>>(whh, wt);
    k_cvt<<<(VOCAB * EMBED + 255) / 256, 256, 0, stream>>>(emb, emb_bf, VOCAB * EMBED);
    k_cvt<<<(VOCAB * HIDDEN + 255) / 256, 256, 0, stream>>>(whyw, why_bf, VOCAB * HIDDEN);
    k_txp_wxh<<<(EMBED * HIDDEN + 255) / 256, 256, 0, stream>>>(wxh, wxh_t);

    // phase 1: xwb[t*64+b][j] = emb[x[b][t]] @ W_xh + b_h
    k_gemm<true, true><<<dim3((SEQ * BATCH) / 64, HIDDEN / 64), 256, 0, stream>>>(
        emb_bf, x, wxh_t, bh, nullptr, xwb, SEQ * BATCH, HIDDEN, EMBED);

    // phase 2: the recurrence (4 blocks x 16 batch rows)
    k_scan_mfma<<<BATCH / ROWS, 512, 0, stream>>>(xwb, wt, h0, hh, hfin);

    // phase 3: logits = hh @ W_hy^T + b
    k_gemm<false, false><<<dim3((BATCH * SEQ) / 64, VOCAB / 64), 256, 0, stream>>>(
        hh, nullptr, why_bf, whyb, logits, nullptr, BATCH * SEQ, VOCAB, HIDDEN);
}

// Round 4
// 3171.165 us; speedup vs baseline: 11.2798x; 1.2416x over previous
//
#include <hip/hip_runtime.h>
#include <hip/hip_bf16.h>
#include <stdint.h>

#define BATCH  64
#define SEQ    1024
#define EMBED  128
#define HIDDEN 512
#define VOCAB  256

using bf16 = __hip_bfloat16;
typedef __attribute__((ext_vector_type(8))) short bf16x8;
typedef __attribute__((ext_vector_type(4))) float f32x4;

__device__ __forceinline__ float bfu(unsigned short u) {
    return __uint_as_float(((unsigned)u) << 16);
}

// ---------------- weight converts ----------------
__global__ void k_cvt(const float* __restrict__ in, bf16* __restrict__ out, int n) {
    int i = blockIdx.x * 256 + threadIdx.x;
    if (i < n) out[i] = __float2bfloat16(in[i]);
}

// W_xh [EMBED][HIDDEN] -> wxh_t [HIDDEN][EMBED] bf16
__global__ void k_txp_wxh(const float* __restrict__ in, bf16* __restrict__ out) {
    int idx = blockIdx.x * 256 + threadIdx.x;   // 65536
    int e = idx >> 9, j = idx & 511;
    out[j * EMBED + e] = __float2bfloat16(in[idx]);
}

// W_hh [K=512][N=512] -> wt [N=512][K=512] bf16
__global__ void k_txp_whh(const float* __restrict__ in, bf16* __restrict__ out) {
    int idx = blockIdx.x * 256 + threadIdx.x;   // 262144
    int k = idx >> 9, n = idx & 511;
    out[n * HIDDEN + k] = __float2bfloat16(in[idx]);
}

// ---------------- bf16 MFMA GEMM:  C[M][N] = A[M][K] * B'[N][K]^T + bias ----------------
template<bool GATHER, bool OUT_BF16>
__global__ __launch_bounds__(256) void k_gemm(
    const bf16* __restrict__ A,       // [M][K]; if GATHER: embedding table [VOCAB][K]
    const int*  __restrict__ xtok,    // tokens [BATCH][SEQ] (GATHER only)
    const bf16* __restrict__ B,       // [N][K]
    const float* __restrict__ bias,   // [N]
    float* __restrict__ Cf,
    bf16*  __restrict__ Cb,
    int M, int N, int K)
{
    __shared__ bf16 As[64][72];
    __shared__ bf16 Bs[64][72];
    const int m0 = blockIdx.x * 64, n0 = blockIdx.y * 64;
    const int tid  = threadIdx.x;
    const int lane = tid & 63, wid = tid >> 6;
    const int wm = wid >> 1, wn = wid & 1;
    const int lrow = tid >> 3, lc8 = tid & 7;

    f32x4 acc[2][2] = {};

    for (int k0 = 0; k0 < K; k0 += 64) {
#pragma unroll
        for (int pass = 0; pass < 2; ++pass) {
            int row = pass * 32 + lrow;
            const bf16* asrc;
            if (GATHER) {
                int m = m0 + row;                 // m = t*BATCH + b
                int t = m >> 6, bb = m & 63;
                int tok = xtok[bb * SEQ + t];
                asrc = A + (size_t)tok * K + k0 + lc8 * 8;
            } else {
                asrc = A + (size_t)(m0 + row) * K + k0 + lc8 * 8;
            }
            *reinterpret_cast<uint4*>(&As[row][lc8 * 8]) = *reinterpret_cast<const uint4*>(asrc);
            *reinterpret_cast<uint4*>(&Bs[row][lc8 * 8]) =
                *reinterpret_cast<const uint4*>(B + (size_t)(n0 + row) * K + k0 + lc8 * 8);
        }
        __syncthreads();
#pragma unroll
        for (int kk = 0; kk < 2; ++kk) {
            bf16x8 af[2], bg[2];
#pragma unroll
            for (int mt = 0; mt < 2; ++mt)
                af[mt] = *reinterpret_cast<const bf16x8*>(
                    &As[wm * 32 + mt * 16 + (lane & 15)][kk * 32 + (lane >> 4) * 8]);
#pragma unroll
            for (int nt = 0; nt < 2; ++nt)
                bg[nt] = *reinterpret_cast<const bf16x8*>(
                    &Bs[wn * 32 + nt * 16 + (lane & 15)][kk * 32 + (lane >> 4) * 8]);
#pragma unroll
            for (int mt = 0; mt < 2; ++mt)
#pragma unroll
                for (int nt = 0; nt < 2; ++nt)
                    acc[mt][nt] = __builtin_amdgcn_mfma_f32_16x16x32_bf16(
                        af[mt], bg[nt], acc[mt][nt], 0, 0, 0);
        }
        __syncthreads();
    }
#pragma unroll
    for (int mt = 0; mt < 2; ++mt) {
        int rbase = m0 + wm * 32 + mt * 16 + (lane >> 4) * 4;
#pragma unroll
        for (int nt = 0; nt < 2; ++nt) {
            int col = n0 + wn * 32 + nt * 16 + (lane & 15);
            float bv = bias[col];
#pragma unroll
            for (int r = 0; r < 4; ++r) {
                float v = acc[mt][nt][r] + bv;
                size_t off = (size_t)(rbase + r) * N + col;
                if (OUT_BF16) Cb[off] = __float2bfloat16(v);
                else          Cf[off] = v;
            }
        }
    }
}

// ---------------- MFMA scan: 4 blocks x 16 batch rows ----------------
// 8 waves; wave w owns N-cols [64w, 64w+64). 16 k-chunks of 32:
//   chunks 0..2   : LDS-resident (wres, 106.5 KB)
//   chunks 3..10  : REGISTER-resident (breg, 128 VGPR/wave = 262 KB of W chip... per CU)
//   chunks 11..15 : streamed from L2 per step (164 KB)
// h double-buffered in LDS -> ONE barrier per step. xw loaded direct to regs.
#define ROWS 16
#define CHK_LDS 3
#define CHK_REG 8
#define WRES_STRIDE (CHK_LDS * 32 + 8)   // 104: +8 pad, 16B-aligned rows, 2-way banks
#define H_STRIDE (HIDDEN + 8)            // 520

__global__ __launch_bounds__(512, 2) void k_scan_mfma(
    const bf16* __restrict__ xwb,   // [SEQ][BATCH][HIDDEN]
    const bf16* __restrict__ wt,    // [HIDDEN n][HIDDEN k]
    const float* __restrict__ h0,   // [BATCH][HIDDEN]
    bf16* __restrict__ hh,          // [BATCH][SEQ][HIDDEN]
    float* __restrict__ hfin)       // [BATCH][HIDDEN]
{
    __shared__ bf16 wres[HIDDEN * WRES_STRIDE];   // 106.5 KB
    __shared__ bf16 h_lds[2][ROWS * H_STRIDE];    // 2 x 16.6 KB

    const int tid  = threadIdx.x;
    const int lane = tid & 63, wid = tid >> 6;
    const int b0   = blockIdx.x * ROWS;
    const int scol = wid * 64;                    // wave's N-col base
    const int lm   = lane & 15, lk = lane >> 4;

    // ---- one-time: resident W chunk rows (1 n-row per thread) ----
    {
        const bf16* src = wt + (size_t)tid * HIDDEN;
        bf16* dst = &wres[tid * WRES_STRIDE];
#pragma unroll
        for (int j = 0; j < (CHK_LDS * 32) / 8; ++j)
            *reinterpret_cast<uint4*>(dst + j * 8) =
                *reinterpret_cast<const uint4*>(src + j * 8);
    }
    // ---- one-time: h0 -> h_lds[0] ----
    {
        int row = tid >> 5, c = (tid & 31) * 16;
        const float* src = h0 + (size_t)(b0 + row) * HIDDEN + c;
        bf16 tmp[16];
#pragma unroll
        for (int j = 0; j < 16; ++j) tmp[j] = __float2bfloat16(src[j]);
        *reinterpret_cast<uint4*>(&h_lds[0][row * H_STRIDE + c])     = *reinterpret_cast<uint4*>(&tmp[0]);
        *reinterpret_cast<uint4*>(&h_lds[0][row * H_STRIDE + c + 8]) = *reinterpret_cast<uint4*>(&tmp[8]);
    }

    // ---- one-time: register-resident B fragments (128 VGPR/wave) ----
    // per (chunk c, n-tile nt): lane holds wt[scol+nt*16+lm][(3+c)*32 + lk*8 .. +8]
    bf16x8 breg[CHK_REG][4];
#pragma unroll
    for (int c = 0; c < CHK_REG; ++c)
#pragma unroll
        for (int nt = 0; nt < 4; ++nt)
            breg[c][nt] = *reinterpret_cast<const bf16x8*>(
                wt + (size_t)(scol + nt * 16 + lm) * HIDDEN + (CHK_LDS + c) * 32 + lk * 8);

    // per-nt base pointers for streamed chunks + LDS-resident chunks
    const bf16* grow[4];
    const bf16* lrow[4];
#pragma unroll
    for (int nt = 0; nt < 4; ++nt) {
        int row = scol + nt * 16 + lm;
        grow[nt] = wt + (size_t)row * HIDDEN + lk * 8;
        lrow[nt] = &wres[row * WRES_STRIDE + lk * 8];
    }

    __syncthreads();

    int p = 0;
    for (int t = 0; t < SEQ; ++t) {
        // xw for this step: direct per-lane loads (held in regs; hidden under MFMA phase)
        const ushort* xbase = reinterpret_cast<const ushort*>(
            xwb + ((size_t)t * BATCH + b0) * HIDDEN);
        ushort xwv[4][4];
#pragma unroll
        for (int nt = 0; nt < 4; ++nt)
#pragma unroll
            for (int r = 0; r < 4; ++r)
                xwv[nt][r] = xbase[(size_t)(lk * 4 + r) * HIDDEN + scol + nt * 16 + lm];

        f32x4 acc[4] = {};
#pragma unroll
        for (int kc = 0; kc < 16; ++kc) {
            bf16x8 af = *reinterpret_cast<const bf16x8*>(
                &h_lds[p][lm * H_STRIDE + kc * 32 + lk * 8]);
#pragma unroll
            for (int nt = 0; nt < 4; ++nt) {
                bf16x8 bg;
                if (kc < CHK_LDS)
                    bg = *reinterpret_cast<const bf16x8*>(lrow[nt] + kc * 32);
                else if (kc < CHK_LDS + CHK_REG)
                    bg = breg[kc - CHK_LDS][nt];
                else
                    bg = *reinterpret_cast<const bf16x8*>(grow[nt] + kc * 32);
                acc[nt] = __builtin_amdgcn_mfma_f32_16x16x32_bf16(af, bg, acc[nt], 0, 0, 0);
            }
        }

        // epilogue: write h_new into the OTHER h buffer (no conflict with readers of h[p])
#pragma unroll
        for (int nt = 0; nt < 4; ++nt) {
            int col = scol + nt * 16 + lm;
#pragma unroll
            for (int r = 0; r < 4; ++r) {
                int m = lk * 4 + r;
                float pre = acc[nt][r] + bfu(xwv[nt][r]);
                float e2  = __expf(2.f * pre);
                float hn  = 1.f - 2.f / (e2 + 1.f);     // tanh(pre)
                bf16 hb   = __float2bfloat16(hn);
                h_lds[p ^ 1][m * H_STRIDE + col] = hb;
                hh[((size_t)(b0 + m) * SEQ + t) * HIDDEN + col] = hb;
                if (t == SEQ - 1) hfin[(size_t)(b0 + m) * HIDDEN + col] = hn;
            }
        }
        p ^= 1;
        __syncthreads();    // single barrier per step
    }
}

// ---------------- launch ----------------
extern "C" void kernel_launch(void* const* d_in, const int* in_sizes, int n_in,
                              void* d_out, int out_size, void* d_ws, size_t ws_size,
                              hipStream_t stream) {
    const int*   x    = (const int*)  d_in[0];
    const float* h0   = (const float*)d_in[1];
    const float* emb  = (const float*)d_in[2];
    const float* wxh  = (const float*)d_in[3];
    const float* whh  = (const float*)d_in[4];
    const float* bh   = (const float*)d_in[5];
    const float* whyw = (const float*)d_in[6];
    const float* whyb = (const float*)d_in[7];

    float* logits = (float*)d_out;                            // [BATCH][SEQ][VOCAB]
    float* hfin   = logits + (size_t)BATCH * SEQ * VOCAB;     // [BATCH][HIDDEN]

    char* p = (char*)d_ws;
    bf16* xwb    = (bf16*)p; p += (size_t)SEQ * BATCH * HIDDEN * 2;
    bf16* hh     = (bf16*)p; p += (size_t)BATCH * SEQ * HIDDEN * 2;
    bf16* wt     = (bf16*)p; p += (size_t)HIDDEN * HIDDEN * 2;
    bf16* wxh_t  = (bf16*)p; p += (size_t)HIDDEN * EMBED * 2;
    bf16* emb_bf = (bf16*)p; p += (size_t)VOCAB * EMBED * 2;
    bf16* why_bf = (bf16*)p; p += (size_t)VOCAB * HIDDEN * 2;

    k_txp_whh<<<(HIDDEN * HIDDEN + 255) / 256, 256, 0, stream>>>(whh, wt);
    k_cvt<<<(VOCAB * EMBED + 255) / 256, 256, 0, stream>>>(emb, emb_bf, VOCAB * EMBED);
    k_cvt<<<(VOCAB * HIDDEN + 255) / 256, 256, 0, stream>>>(whyw, why_bf, VOCAB * HIDDEN);
    k_txp_wxh<<<(EMBED * HIDDEN + 255) / 256, 256, 0, stream>>>(wxh, wxh_t);

    // phase 1: xwb[t*64+b][j] = emb[x[b][t]] @ W_xh + b_h
    k_gemm<true, true><<<dim3((SEQ * BATCH) / 64, HIDDEN / 64), 256, 0, stream>>>(
        emb_bf, x, wxh_t, bh, nullptr, xwb, SEQ * BATCH, HIDDEN, EMBED);

    // phase 2: the recurrence (4 blocks x 16 batch rows)
    k_scan_mfma<<<BATCH / ROWS, 512, 0, stream>>>(xwb, wt, h0, hh, hfin);

    // phase 3: logits = hh @ W_hy^T + b
    k_gemm<false, false><<<dim3((BATCH * SEQ) / 64, VOCAB / 64), 256, 0, stream>>>(
        hh, nullptr, why_bf, whyb, logits, nullptr, BATCH * SEQ, VOCAB, HIDDEN);
}